// Round 15
// baseline (138.880 us; speedup 1.0000x reference)
//
#include <hip/hip_runtime.h>

#define BB 8
#define CC 128

typedef _Float16 f16x4 __attribute__((ext_vector_type(4)));
typedef float f32x4 __attribute__((ext_vector_type(4)));
typedef __fp16 fp16x2 __attribute__((ext_vector_type(2)));

// Pack 2 f32 -> 2 f16 in one v_cvt_pkrtz_f16_f32.
__device__ __forceinline__ unsigned int pack2(float a, float b) {
  union { fp16x2 h; unsigned int u; } cv;
  cv.h = __builtin_amdgcn_cvt_pkrtz(a, b);
  return cv.u;
}

// Bilinear sample from a zero-border padded LDS plane.
__device__ __forceinline__ float sample_pad(const float* __restrict__ pl, int stride,
                                            float WF, float ix, float iy) {
  ix = fminf(fmaxf(ix, -1.0f), WF);
  iy = fminf(fmaxf(iy, -1.0f), WF);
  float x0f = floorf(ix), y0f = floorf(iy);
  float wx = ix - x0f, wy = iy - y0f;
  int xi = (int)x0f + 1, yi = (int)y0f + 1;
  const float* p0 = pl + yi * stride + xi;
  float v00 = p0[0], v01 = p0[1], v10 = p0[stride], v11 = p0[stride + 1];
  return (1.0f - wy) * ((1.0f - wx) * v00 + wx * v01) +
         wy * ((1.0f - wx) * v10 + wx * v11);
}

// Factorized box mask.
__device__ __forceinline__ float box_mask(float bix, float biy, float WM1) {
  float bx0 = floorf(bix), by0 = floorf(biy);
  float bwx = bix - bx0, bwy = biy - by0;
  float mx = (((bx0 >= 0.0f) && (bx0 <= WM1)) ? (1.0f - bwx) : 0.0f) +
             (((bx0 >= -1.0f) && (bx0 <= WM1 - 1.0f)) ? bwx : 0.0f);
  float my = (((by0 >= 0.0f) && (by0 <= WM1)) ? (1.0f - bwy) : 0.0f) +
             (((by0 >= -1.0f) && (by0 <= WM1 - 1.0f)) ? bwy : 0.0f);
  return mx * my;
}

// ---------------- fused inLay: combine -> padded LDS + sample + box mask ----------
__global__ __launch_bounds__(256) void inlay_sample_kernel(
    const float* __restrict__ x, const float* __restrict__ lin,
    const float* __restrict__ geo, const float* __restrict__ box,
    const float* __restrict__ db, float* __restrict__ out,
    float* __restrict__ head) {
  const int H = 64, W = 64, HW = 4096;
  __shared__ float cp[67 * 68];
  int bc = blockIdx.x;
  int c = bc & (CC - 1);
  int b = bc >> 7;
  int tid = threadIdx.x;
  if (bc == 0 && tid < 80) head[tid] = db[tid % 10];  // bias init for atomic dense
  const float* xb = x + (size_t)b * 3 * HW;

  float w0 = lin[c * 3 + 0], w1 = lin[c * 3 + 1], w2 = lin[c * 3 + 2];

  if (tid < 68) {
    cp[tid] = 0.0f; cp[65 * 68 + tid] = 0.0f; cp[66 * 68 + tid] = 0.0f;
  } else if (tid < 132) {
    int r = tid - 67;
    cp[r * 68 + 0] = 0.0f; cp[r * 68 + 65] = 0.0f; cp[r * 68 + 66] = 0.0f;
  }

#pragma unroll
  for (int k = 0; k < 4; ++k) {
    int i4 = tid + k * 256;
    int base = i4 * 4;
    float4 f0 = *reinterpret_cast<const float4*>(&xb[base]);
    float4 f1 = *reinterpret_cast<const float4*>(&xb[HW + base]);
    float4 f2 = *reinterpret_cast<const float4*>(&xb[2 * HW + base]);
    int h = i4 >> 4, w = (i4 & 15) * 4;
    float* d = &cp[(h + 1) * 68 + w + 1];
    d[0] = w0 * f0.x + w1 * f1.x + w2 * f2.x;
    d[1] = w0 * f0.y + w1 * f1.y + w2 * f2.y;
    d[2] = w0 * f0.z + w1 * f1.z + w2 * f2.z;
    d[3] = w0 * f0.w + w1 * f1.w + w2 * f2.w;
  }
  __syncthreads();

  const float* g = geo + c * 6;
  const float* bx = box + c * 6;
  float a0 = 32.0f * g[0], a1 = 32.0f * g[1], a2 = 32.0f * g[2] + 31.5f;
  float a3 = 32.0f * g[3], a4 = 32.0f * g[4], a5 = 32.0f * g[5] + 31.5f;
  float c0 = 32.0f * bx[0], c1 = 32.0f * bx[1], c2 = 32.0f * bx[2] + 31.5f;
  float c3 = 32.0f * bx[3], c4 = 32.0f * bx[4], c5 = 32.0f * bx[5] + 31.5f;
  float* o = out + ((size_t)b * CC + c) * HW;

  // 4 contiguous px/thread per chunk: shared row terms + float4 stores.
#pragma unroll
  for (int k = 0; k < 4; ++k) {
    int p0 = k * 1024 + tid * 4;
    int h = p0 >> 6, w0i = p0 & 63;
    float ys = (2.0f * h + 1.0f) / H - 1.0f;
    float tix = fmaf(a1, ys, a2);
    float tiy = fmaf(a4, ys, a5);
    float tbx = fmaf(c1, ys, c2);
    float tby = fmaf(c4, ys, c5);
    float4 rv;
    float* rp = &rv.x;
#pragma unroll
    for (int d = 0; d < 4; ++d) {
      float xs = (2.0f * (w0i + d) + 1.0f) / W - 1.0f;
      float ix = fmaf(a0, xs, tix);
      float iy = fmaf(a3, xs, tiy);
      float samp = sample_pad(cp, 68, 64.0f, ix, iy);
      float bix = fmaf(c0, xs, tbx);
      float biy = fmaf(c3, xs, tby);
      rp[d] = samp * box_mask(bix, biy, 63.0f);
    }
    *reinterpret_cast<float4*>(&o[p0]) = rv;
  }
}

// ---------------- layer-0 GEMM via f16 MFMA: 64x64 tile, single-stage LDS ----------
__global__ __launch_bounds__(256) void gemm64_mfma_kernel(
    const float* __restrict__ lin, const float* __restrict__ x,
    float* __restrict__ y) {
  const int Ci = 128, HW = 4096;
  __shared__ unsigned int A_lds[64 * 66];
  __shared__ unsigned int B_lds[64 * 66];
  int b = blockIdx.z;
  int row0 = blockIdx.y * 64, col0 = blockIdx.x * 64;
  const float* xb = x + (size_t)b * Ci * HW;
  float* yb = y + (size_t)b * CC * HW;
  int tid = threadIdx.x;

  {
    int row = tid >> 2, kc = (tid & 3) * 32;
    const float* ap = &lin[(row0 + row) * Ci + kc];
    unsigned int* dst = &A_lds[row * 66 + (kc >> 1)];
#pragma unroll
    for (int i = 0; i < 8; ++i) {
      float4 v = *reinterpret_cast<const float4*>(ap + i * 4);
      dst[i * 2] = pack2(v.x, v.y);
      dst[i * 2 + 1] = pack2(v.z, v.w);
    }
  }
  {
    int kp = tid >> 2, cg = (tid & 3) * 16;
    const float* b0p = &xb[(size_t)(2 * kp) * HW + col0 + cg];
    const float* b1p = &xb[(size_t)(2 * kp + 1) * HW + col0 + cg];
#pragma unroll
    for (int q = 0; q < 4; ++q) {
      float4 v0 = *reinterpret_cast<const float4*>(b0p + q * 4);
      float4 v1 = *reinterpret_cast<const float4*>(b1p + q * 4);
      unsigned int* bp_ = &B_lds[(cg + q * 4) * 66 + kp];
      bp_[0 * 66] = pack2(v0.x, v1.x);
      bp_[1 * 66] = pack2(v0.y, v1.y);
      bp_[2 * 66] = pack2(v0.z, v1.z);
      bp_[3 * 66] = pack2(v0.w, v1.w);
    }
  }
  __syncthreads();

  int w = tid >> 6, l = tid & 63;
  int lr = l & 15, lq = l >> 4;
  f32x4 acc0 = {0.f, 0.f, 0.f, 0.f};
  f32x4 acc1 = acc0, acc2 = acc0, acc3 = acc0;
  const unsigned int* arow = &A_lds[(w * 16 + lr) * 66 + 2 * lq];
  const unsigned int* bcol = &B_lds[lr * 66 + 2 * lq];
#pragma unroll
  for (int s = 0; s < 8; ++s) {
    f16x4 af = *reinterpret_cast<const f16x4*>(arow + s * 8);
    f16x4 b0 = *reinterpret_cast<const f16x4*>(bcol + 0 * 16 * 66 + s * 8);
    f16x4 b1 = *reinterpret_cast<const f16x4*>(bcol + 1 * 16 * 66 + s * 8);
    f16x4 b2 = *reinterpret_cast<const f16x4*>(bcol + 2 * 16 * 66 + s * 8);
    f16x4 b3 = *reinterpret_cast<const f16x4*>(bcol + 3 * 16 * 66 + s * 8);
    acc0 = __builtin_amdgcn_mfma_f32_16x16x16f16(af, b0, acc0, 0, 0, 0);
    acc1 = __builtin_amdgcn_mfma_f32_16x16x16f16(af, b1, acc1, 0, 0, 0);
    acc2 = __builtin_amdgcn_mfma_f32_16x16x16f16(af, b2, acc2, 0, 0, 0);
    acc3 = __builtin_amdgcn_mfma_f32_16x16x16f16(af, b3, acc3, 0, 0, 0);
  }
#pragma unroll
  for (int i = 0; i < 4; ++i) {
    float* yr = yb + (size_t)(row0 + w * 16 + lq * 4 + i) * HW + col0 + lr;
    yr[0]  = acc0[i];
    yr[16] = acc1[i];
    yr[32] = acc2[i];
    yr[48] = acc3[i];
  }
}

// ---------------- 32x32-layer GEMM via f16 MFMA: M=32ch x N=64px, K=128 ----------
__global__ __launch_bounds__(256) void gemm32_mfma_kernel(
    const float* __restrict__ lin, const float* __restrict__ x,
    float* __restrict__ y) {
  const int Ci = 128, HW = 1024;
  __shared__ unsigned int A_lds[32 * 66];
  __shared__ unsigned int B_lds[64 * 66];
  int b = blockIdx.z;
  int row0 = blockIdx.y * 32, col0 = blockIdx.x * 64;
  const float* xb = x + (size_t)b * Ci * HW;
  float* yb = y + (size_t)b * CC * HW;
  int tid = threadIdx.x;

  {
    int row = tid >> 3, kc = (tid & 7) * 16;
    const float* ap = &lin[(row0 + row) * Ci + kc];
    unsigned int* dst = &A_lds[row * 66 + (kc >> 1)];
#pragma unroll
    for (int i = 0; i < 4; ++i) {
      float4 v = *reinterpret_cast<const float4*>(ap + i * 4);
      dst[i * 2] = pack2(v.x, v.y);
      dst[i * 2 + 1] = pack2(v.z, v.w);
    }
  }
  {
    int kp = tid >> 2, cg = (tid & 3) * 16;
    const float* b0p = &xb[(size_t)(2 * kp) * HW + col0 + cg];
    const float* b1p = &xb[(size_t)(2 * kp + 1) * HW + col0 + cg];
#pragma unroll
    for (int q = 0; q < 4; ++q) {
      float4 v0 = *reinterpret_cast<const float4*>(b0p + q * 4);
      float4 v1 = *reinterpret_cast<const float4*>(b1p + q * 4);
      unsigned int* bp_ = &B_lds[(cg + q * 4) * 66 + kp];
      bp_[0 * 66] = pack2(v0.x, v1.x);
      bp_[1 * 66] = pack2(v0.y, v1.y);
      bp_[2 * 66] = pack2(v0.z, v1.z);
      bp_[3 * 66] = pack2(v0.w, v1.w);
    }
  }
  __syncthreads();

  int w = tid >> 6, l = tid & 63;
  int lr = l & 15, lq = l >> 4;
  int rs = (w & 1) * 16;
  int ct0 = (w >> 1) * 2;
  f32x4 acc0 = {0.f, 0.f, 0.f, 0.f};
  f32x4 acc1 = acc0;
  const unsigned int* arow = &A_lds[(rs + lr) * 66 + 2 * lq];
  const unsigned int* bc0 = &B_lds[(ct0 * 16 + lr) * 66 + 2 * lq];
  const unsigned int* bc1 = &B_lds[((ct0 + 1) * 16 + lr) * 66 + 2 * lq];
#pragma unroll
  for (int s = 0; s < 8; ++s) {
    f16x4 af = *reinterpret_cast<const f16x4*>(arow + s * 8);
    f16x4 b0 = *reinterpret_cast<const f16x4*>(bc0 + s * 8);
    f16x4 b1 = *reinterpret_cast<const f16x4*>(bc1 + s * 8);
    acc0 = __builtin_amdgcn_mfma_f32_16x16x16f16(af, b0, acc0, 0, 0, 0);
    acc1 = __builtin_amdgcn_mfma_f32_16x16x16f16(af, b1, acc1, 0, 0, 0);
  }
#pragma unroll
  for (int i = 0; i < 4; ++i) {
    float* yr = yb + (size_t)(row0 + rs + lq * 4 + i) * HW + col0 + ct0 * 16 + lr;
    yr[0]  = acc0[i];
    yr[16] = acc1[i];
  }
}

// ---------------- fused sample(64x64) + MaxPool2d_G -> 32x32, 256 threads ---------
// Phase 1: 4 contiguous px/thread + b128 LDS writes; phases 2/3 ring-slide (r14).
__global__ __launch_bounds__(256, 4) void sampmax_kernel(
    const float* __restrict__ y, const float* __restrict__ geo,
    const float* __restrict__ box, float* __restrict__ out) {
  __shared__ __align__(16) float sp[64 * 68];
  __shared__ __align__(16) float arena[67 * 68];  // pl (ph0-1) then cb2[u*65+r] (ph2-3)
  __shared__ float wv[4];
  __shared__ int wi[4];
  __shared__ int am_s;
  float* pl = arena;
  float* cb2 = arena;

  int bc = blockIdx.x;
  int c = bc & (CC - 1);
  int tid = threadIdx.x;

  if (tid < 68) {
    pl[tid] = 0.0f; pl[65 * 68 + tid] = 0.0f; pl[66 * 68 + tid] = 0.0f;
  } else if (tid < 132) {
    int r = tid - 67;
    pl[r * 68 + 0] = 0.0f; pl[r * 68 + 65] = 0.0f; pl[r * 68 + 66] = 0.0f;
  }
  {
    const float* plane = y + (size_t)bc * 4096;
#pragma unroll
    for (int k = 0; k < 4; ++k) {
      int i4 = tid + k * 256;
      float4 f = *reinterpret_cast<const float4*>(&plane[i4 * 4]);
      int h = i4 >> 4, w = (i4 & 15) * 4;
      float* d = &pl[(h + 1) * 68 + w + 1];
      d[0] = f.x; d[1] = f.y; d[2] = f.z; d[3] = f.w;
    }
  }
  __syncthreads();

  {
    const float* g = geo + c * 6;
    const float* bx = box + c * 6;
    float a0 = 32.0f * g[0], a1 = 32.0f * g[1], a2 = 32.0f * g[2] + 31.5f;
    float a3 = 32.0f * g[3], a4 = 32.0f * g[4], a5 = 32.0f * g[5] + 31.5f;
    float c0 = 32.0f * bx[0], c1 = 32.0f * bx[1], c2 = 32.0f * bx[2] + 31.5f;
    float c3 = 32.0f * bx[3], c4 = 32.0f * bx[4], c5 = 32.0f * bx[5] + 31.5f;
#pragma unroll
    for (int k = 0; k < 4; ++k) {
      int p0 = k * 1024 + tid * 4;
      int h = p0 >> 6, w0i = p0 & 63;
      float ys = (2.0f * h + 1.0f) / 64.0f - 1.0f;
      float tix = fmaf(a1, ys, a2);
      float tiy = fmaf(a4, ys, a5);
      float tbx = fmaf(c1, ys, c2);
      float tby = fmaf(c4, ys, c5);
      float4 rv;
      float* rp = &rv.x;
#pragma unroll
      for (int d = 0; d < 4; ++d) {
        float xs = (2.0f * (w0i + d) + 1.0f) / 64.0f - 1.0f;
        float ix = fmaf(a0, xs, tix);
        float iy = fmaf(a3, xs, tiy);
        float samp = sample_pad(pl, 68, 64.0f, ix, iy);
        float bix = fmaf(c0, xs, tbx);
        float biy = fmaf(c3, xs, tby);
        rp[d] = samp * box_mask(bix, biy, 63.0f);
      }
      *reinterpret_cast<float4*>(&sp[h * 68 + w0i]) = rv;
    }
  }
  __syncthreads();

  // Phase 2: vertical 32-row box sums. Wave w -> output rows w*16..w*16+15; lane = col.
  {
    int wv_ = tid >> 6;
    int u = tid & 63;
    int R0 = wv_ * 16;
    float ring[32];
    float S = 0.f;
#pragma unroll
    for (int j = 0; j < 32; ++j) {
      int r = R0 - 16 + j;
      bool valid = (r >= 0) && (r < 64);
      int rc = valid ? r : 0;
      float v = sp[rc * 68 + u];
      v = valid ? v : 0.0f;
      ring[j] = v;
      S += v;
    }
#pragma unroll
    for (int t = 0; t < 16; ++t) {
      cb2[u * 65 + R0 + t] = S;
      int rin = R0 + 16 + t;
      bool vin = rin < 64;
      int rc = vin ? rin : 0;
      float fin = sp[rc * 68 + u];
      fin = vin ? fin : 0.0f;
      S += fin - ring[t];
    }
  }
  __syncthreads();

  // Phase 3: horizontal 32-col box sums + argmax. Wave w -> cols w*16..; lane = row.
  float best = -3.402823466e+38f;
  int bidx = 0x7fffffff;
  {
    int wv_ = tid >> 6;
    int lane_r = tid & 63;
    int C0 = wv_ * 16;
    float ring2[32];
    float S2 = 0.f;
#pragma unroll
    for (int j = 0; j < 32; ++j) {
      int uu = C0 - 16 + j;
      bool valid = (uu >= 0) && (uu < 64);
      int uc = valid ? uu : 0;
      float v = cb2[uc * 65 + lane_r];
      v = valid ? v : 0.0f;
      ring2[j] = v;
      S2 += v;
    }
#pragma unroll
    for (int t = 0; t < 16; ++t) {
      int i = (lane_r << 6) + C0 + t;
      if (S2 > best) { best = S2; bidx = i; }
      int uin = C0 + 16 + t;
      bool vin = uin < 64;
      int uc = vin ? uin : 0;
      float fin = cb2[uc * 65 + lane_r];
      fin = vin ? fin : 0.0f;
      S2 += fin - ring2[t];
    }
  }
#pragma unroll
  for (int off = 32; off > 0; off >>= 1) {
    float v2 = __shfl_down(best, off);
    int i2 = __shfl_down(bidx, off);
    if (v2 > best || (v2 == best && i2 < bidx)) { best = v2; bidx = i2; }
  }
  if ((tid & 63) == 0) { wv[tid >> 6] = best; wi[tid >> 6] = bidx; }
  __syncthreads();
  if (tid == 0) {
    float bv = wv[0]; int bi = wi[0];
#pragma unroll
    for (int k = 1; k < 4; ++k)
      if (wv[k] > bv || (wv[k] == bv && wi[k] < bi)) { bv = wv[k]; bi = wi[k]; }
    am_s = bi;
  }
  __syncthreads();

  int am = am_s;
  int r = am >> 6, cx = am & 63;
  float* o = out + (size_t)bc * 1024;
#pragma unroll
  for (int k = 0; k < 4; ++k) {
    int idx = tid + k * 256;
    int oi = idx >> 5, oj = idx & 31;
    int rr = r + oi - 16, cj = cx + oj - 16;
    bool v = (rr >= 0) && (rr < 64) && (cj >= 0) && (cj < 64);
    int rrc = v ? rr : 0, cjc = v ? cj : 0;
    o[idx] = v ? sp[rrc * 68 + cjc] : 0.0f;
  }
}

// ---------------- 32x32 sample (+optional mean-pool + dense-head atomics) --------
template <bool POOL>
__global__ __launch_bounds__(256) void sample32_kernel(
    const float* __restrict__ y, const float* __restrict__ geo,
    const float* __restrict__ box, float* __restrict__ out,
    const float* __restrict__ dw, float* __restrict__ head) {
  const int W = 32, HW = 1024;
  __shared__ float pl[35 * 36];
  __shared__ float wred[4];
  int bc = blockIdx.x;
  int c = bc & (CC - 1);
  int b = bc >> 7;
  int tid = threadIdx.x;

  if (tid < 36) {
    pl[tid] = 0.0f; pl[33 * 36 + tid] = 0.0f; pl[34 * 36 + tid] = 0.0f;
  } else if (tid < 68) {
    int r = tid - 35;
    pl[r * 36 + 0] = 0.0f; pl[r * 36 + 33] = 0.0f; pl[r * 36 + 34] = 0.0f; pl[r * 36 + 35] = 0.0f;
  }
  {
    const float* plane = y + (size_t)bc * HW;
    float4 f = *reinterpret_cast<const float4*>(&plane[tid * 4]);
    int h = tid >> 3, w = (tid & 7) * 4;
    float* d = &pl[(h + 1) * 36 + w + 1];
    d[0] = f.x; d[1] = f.y; d[2] = f.z; d[3] = f.w;
  }
  __syncthreads();

  const float* g = geo + c * 6;
  const float* bxp = box + c * 6;
  float a0 = 16.0f * g[0], a1 = 16.0f * g[1], a2 = 16.0f * g[2] + 15.5f;
  float a3 = 16.0f * g[3], a4 = 16.0f * g[4], a5 = 16.0f * g[5] + 15.5f;
  float c0 = 16.0f * bxp[0], c1 = 16.0f * bxp[1], c2 = 16.0f * bxp[2] + 15.5f;
  float c3 = 16.0f * bxp[3], c4 = 16.0f * bxp[4], c5 = 16.0f * bxp[5] + 15.5f;
  float* o = out + (size_t)bc * HW;
  float psum = 0.f;
  {
    int p0 = tid * 4;
    int h = p0 >> 5, w0i = p0 & 31;
    float ys = (2.0f * h + 1.0f) / W - 1.0f;
    float tix = fmaf(a1, ys, a2);
    float tiy = fmaf(a4, ys, a5);
    float tbx = fmaf(c1, ys, c2);
    float tby = fmaf(c4, ys, c5);
    float4 rv;
    float* rp = &rv.x;
#pragma unroll
    for (int d = 0; d < 4; ++d) {
      float xs = (2.0f * (w0i + d) + 1.0f) / W - 1.0f;
      float ix = fmaf(a0, xs, tix);
      float iy = fmaf(a3, xs, tiy);
      float samp = sample_pad(pl, 36, 32.0f, ix, iy);
      float bix = fmaf(c0, xs, tbx);
      float biy = fmaf(c3, xs, tby);
      float res = samp * box_mask(bix, biy, 31.0f);
      rp[d] = res;
      if (POOL) psum += res;
    }
    *reinterpret_cast<float4*>(&o[p0]) = rv;
  }
  if (POOL) {
    int lane = tid & 63, wid = tid >> 6;
    float r = psum;
#pragma unroll
    for (int off = 32; off > 0; off >>= 1) r += __shfl_down(r, off);
    if (lane == 0) wred[wid] = r;
    __syncthreads();
    if (tid < 10) {
      float t = (wred[0] + wred[1] + wred[2] + wred[3]) * (1.0f / 1024.0f);
      atomicAdd(&head[b * 10 + tid], t * dw[tid * 128 + c]);
    }
  }
}

extern "C" void kernel_launch(void* const* d_in, const int* in_sizes, int n_in,
                              void* d_out, int out_size, void* d_ws, size_t ws_size,
                              hipStream_t stream) {
  const float* x     = (const float*)d_in[0];   // [8,3,64,64]
  const float* geo0  = (const float*)d_in[1];   // [128,2,3]
  const float* lin0  = (const float*)d_in[2];   // [128,3]
  const float* box0  = (const float*)d_in[3];   // [128,2,3]
  const float* geos  = (const float*)d_in[4];   // [3,128,2,3]
  const float* lins  = (const float*)d_in[5];   // [3,128,128]
  const float* boxes = (const float*)d_in[6];   // [3,128,2,3]
  const float* dw    = (const float*)d_in[7];   // [10,128]
  const float* db    = (const float*)d_in[8];   // [10]

  float* out  = (float*)d_out;      // [8,10] then feat [8,128,32,32]
  float* feat = out + 80;
  float* ws   = (float*)d_ws;
  float* ws0  = ws;                 // 16 MB regions
  float* ws1  = ws + 4194304;
  float* ws2  = ws + 8388608;

  // inLay: fused combine(Ci=3) + sample -> ws1; also writes head bias
  inlay_sample_kernel<<<dim3(BB * CC), 256, 0, stream>>>(x, lin0, geo0, box0, db, ws1, out);
  // layer 0: f16-MFMA GEMM (64x64 tiles) -> fused sample+maxpool -> 32x32
  gemm64_mfma_kernel<<<dim3(64, 2, BB), 256, 0, stream>>>(lins, ws1, ws0);
  sampmax_kernel<<<dim3(BB * CC), 256, 0, stream>>>(ws0, geos, boxes, ws1);
  // layer 2: f16-MFMA GEMM then sample
  gemm32_mfma_kernel<<<dim3(16, 4, BB), 256, 0, stream>>>(lins + 16384, ws1, ws2);
  sample32_kernel<false><<<dim3(BB * CC), 256, 0, stream>>>(ws2, geos + 768, boxes + 768, ws0, nullptr, nullptr);
  // layer 3: f16-MFMA GEMM then sample + mean-pool + dense head
  gemm32_mfma_kernel<<<dim3(16, 4, BB), 256, 0, stream>>>(lins + 32768, ws0, ws2);
  sample32_kernel<true><<<dim3(BB * CC), 256, 0, stream>>>(ws2, geos + 1536, boxes + 1536, feat, dw, out);
}

// Round 16
// 136.561 us; speedup vs baseline: 1.0170x; 1.0170x over previous
//
#include <hip/hip_runtime.h>

#define BB 8
#define CC 128

typedef _Float16 f16x4 __attribute__((ext_vector_type(4)));
typedef float f32x4 __attribute__((ext_vector_type(4)));
typedef __fp16 fp16x2 __attribute__((ext_vector_type(2)));

// Pack 2 f32 -> 2 f16 in one v_cvt_pkrtz_f16_f32.
__device__ __forceinline__ unsigned int pack2(float a, float b) {
  union { fp16x2 h; unsigned int u; } cv;
  cv.h = __builtin_amdgcn_cvt_pkrtz(a, b);
  return cv.u;
}

// Bilinear sample from a zero-border padded LDS plane.
__device__ __forceinline__ float sample_pad(const float* __restrict__ pl, int stride,
                                            float WF, float ix, float iy) {
  ix = fminf(fmaxf(ix, -1.0f), WF);
  iy = fminf(fmaxf(iy, -1.0f), WF);
  float x0f = floorf(ix), y0f = floorf(iy);
  float wx = ix - x0f, wy = iy - y0f;
  int xi = (int)x0f + 1, yi = (int)y0f + 1;
  const float* p0 = pl + yi * stride + xi;
  float v00 = p0[0], v01 = p0[1], v10 = p0[stride], v11 = p0[stride + 1];
  return (1.0f - wy) * ((1.0f - wx) * v00 + wx * v01) +
         wy * ((1.0f - wx) * v10 + wx * v11);
}

// Factorized box mask.
__device__ __forceinline__ float box_mask(float bix, float biy, float WM1) {
  float bx0 = floorf(bix), by0 = floorf(biy);
  float bwx = bix - bx0, bwy = biy - by0;
  float mx = (((bx0 >= 0.0f) && (bx0 <= WM1)) ? (1.0f - bwx) : 0.0f) +
             (((bx0 >= -1.0f) && (bx0 <= WM1 - 1.0f)) ? bwx : 0.0f);
  float my = (((by0 >= 0.0f) && (by0 <= WM1)) ? (1.0f - bwy) : 0.0f) +
             (((by0 >= -1.0f) && (by0 <= WM1 - 1.0f)) ? bwy : 0.0f);
  return mx * my;
}

// ---------------- fused inLay: combine -> padded LDS + sample + box mask ----------
__global__ __launch_bounds__(256) void inlay_sample_kernel(
    const float* __restrict__ x, const float* __restrict__ lin,
    const float* __restrict__ geo, const float* __restrict__ box,
    const float* __restrict__ db, float* __restrict__ out,
    float* __restrict__ head) {
  const int H = 64, W = 64, HW = 4096;
  __shared__ float cp[67 * 68];
  int bc = blockIdx.x;
  int c = bc & (CC - 1);
  int b = bc >> 7;
  int tid = threadIdx.x;
  if (bc == 0 && tid < 80) head[tid] = db[tid % 10];  // bias init for atomic dense
  const float* xb = x + (size_t)b * 3 * HW;

  float w0 = lin[c * 3 + 0], w1 = lin[c * 3 + 1], w2 = lin[c * 3 + 2];

  if (tid < 68) {
    cp[tid] = 0.0f; cp[65 * 68 + tid] = 0.0f; cp[66 * 68 + tid] = 0.0f;
  } else if (tid < 132) {
    int r = tid - 67;
    cp[r * 68 + 0] = 0.0f; cp[r * 68 + 65] = 0.0f; cp[r * 68 + 66] = 0.0f;
  }

#pragma unroll
  for (int k = 0; k < 4; ++k) {
    int i4 = tid + k * 256;
    int base = i4 * 4;
    float4 f0 = *reinterpret_cast<const float4*>(&xb[base]);
    float4 f1 = *reinterpret_cast<const float4*>(&xb[HW + base]);
    float4 f2 = *reinterpret_cast<const float4*>(&xb[2 * HW + base]);
    int h = i4 >> 4, w = (i4 & 15) * 4;
    float* d = &cp[(h + 1) * 68 + w + 1];
    d[0] = w0 * f0.x + w1 * f1.x + w2 * f2.x;
    d[1] = w0 * f0.y + w1 * f1.y + w2 * f2.y;
    d[2] = w0 * f0.z + w1 * f1.z + w2 * f2.z;
    d[3] = w0 * f0.w + w1 * f1.w + w2 * f2.w;
  }
  __syncthreads();

  const float* g = geo + c * 6;
  const float* bx = box + c * 6;
  float a0 = 32.0f * g[0], a1 = 32.0f * g[1], a2 = 32.0f * g[2] + 31.5f;
  float a3 = 32.0f * g[3], a4 = 32.0f * g[4], a5 = 32.0f * g[5] + 31.5f;
  float c0 = 32.0f * bx[0], c1 = 32.0f * bx[1], c2 = 32.0f * bx[2] + 31.5f;
  float c3 = 32.0f * bx[3], c4 = 32.0f * bx[4], c5 = 32.0f * bx[5] + 31.5f;
  float* o = out + ((size_t)b * CC + c) * HW;

#pragma unroll
  for (int k = 0; k < 16; ++k) {
    int px = tid + k * 256;
    int h = px >> 6, w = px & 63;
    float xs = (2.0f * w + 1.0f) / W - 1.0f;
    float ys = (2.0f * h + 1.0f) / H - 1.0f;
    float ix = fmaf(a0, xs, fmaf(a1, ys, a2));
    float iy = fmaf(a3, xs, fmaf(a4, ys, a5));
    float samp = sample_pad(cp, 68, 64.0f, ix, iy);
    float bix = fmaf(c0, xs, fmaf(c1, ys, c2));
    float biy = fmaf(c3, xs, fmaf(c4, ys, c5));
    o[px] = samp * box_mask(bix, biy, 63.0f);
  }
}

// ---------------- layer-0 GEMM via f16 MFMA: 64x64 tile, single-stage LDS ----------
__global__ __launch_bounds__(256) void gemm64_mfma_kernel(
    const float* __restrict__ lin, const float* __restrict__ x,
    float* __restrict__ y) {
  const int Ci = 128, HW = 4096;
  __shared__ unsigned int A_lds[64 * 66];
  __shared__ unsigned int B_lds[64 * 66];
  int b = blockIdx.z;
  int row0 = blockIdx.y * 64, col0 = blockIdx.x * 64;
  const float* xb = x + (size_t)b * Ci * HW;
  float* yb = y + (size_t)b * CC * HW;
  int tid = threadIdx.x;

  {
    int row = tid >> 2, kc = (tid & 3) * 32;
    const float* ap = &lin[(row0 + row) * Ci + kc];
    unsigned int* dst = &A_lds[row * 66 + (kc >> 1)];
#pragma unroll
    for (int i = 0; i < 8; ++i) {
      float4 v = *reinterpret_cast<const float4*>(ap + i * 4);
      dst[i * 2] = pack2(v.x, v.y);
      dst[i * 2 + 1] = pack2(v.z, v.w);
    }
  }
  {
    int kp = tid >> 2, cg = (tid & 3) * 16;
    const float* b0p = &xb[(size_t)(2 * kp) * HW + col0 + cg];
    const float* b1p = &xb[(size_t)(2 * kp + 1) * HW + col0 + cg];
#pragma unroll
    for (int q = 0; q < 4; ++q) {
      float4 v0 = *reinterpret_cast<const float4*>(b0p + q * 4);
      float4 v1 = *reinterpret_cast<const float4*>(b1p + q * 4);
      unsigned int* bp_ = &B_lds[(cg + q * 4) * 66 + kp];
      bp_[0 * 66] = pack2(v0.x, v1.x);
      bp_[1 * 66] = pack2(v0.y, v1.y);
      bp_[2 * 66] = pack2(v0.z, v1.z);
      bp_[3 * 66] = pack2(v0.w, v1.w);
    }
  }
  __syncthreads();

  int w = tid >> 6, l = tid & 63;
  int lr = l & 15, lq = l >> 4;
  f32x4 acc0 = {0.f, 0.f, 0.f, 0.f};
  f32x4 acc1 = acc0, acc2 = acc0, acc3 = acc0;
  const unsigned int* arow = &A_lds[(w * 16 + lr) * 66 + 2 * lq];
  const unsigned int* bcol = &B_lds[lr * 66 + 2 * lq];
#pragma unroll
  for (int s = 0; s < 8; ++s) {
    f16x4 af = *reinterpret_cast<const f16x4*>(arow + s * 8);
    f16x4 b0 = *reinterpret_cast<const f16x4*>(bcol + 0 * 16 * 66 + s * 8);
    f16x4 b1 = *reinterpret_cast<const f16x4*>(bcol + 1 * 16 * 66 + s * 8);
    f16x4 b2 = *reinterpret_cast<const f16x4*>(bcol + 2 * 16 * 66 + s * 8);
    f16x4 b3 = *reinterpret_cast<const f16x4*>(bcol + 3 * 16 * 66 + s * 8);
    acc0 = __builtin_amdgcn_mfma_f32_16x16x16f16(af, b0, acc0, 0, 0, 0);
    acc1 = __builtin_amdgcn_mfma_f32_16x16x16f16(af, b1, acc1, 0, 0, 0);
    acc2 = __builtin_amdgcn_mfma_f32_16x16x16f16(af, b2, acc2, 0, 0, 0);
    acc3 = __builtin_amdgcn_mfma_f32_16x16x16f16(af, b3, acc3, 0, 0, 0);
  }
#pragma unroll
  for (int i = 0; i < 4; ++i) {
    float* yr = yb + (size_t)(row0 + w * 16 + lq * 4 + i) * HW + col0 + lr;
    yr[0]  = acc0[i];
    yr[16] = acc1[i];
    yr[32] = acc2[i];
    yr[48] = acc3[i];
  }
}

// ---------------- 32x32-layer GEMM via f16 MFMA: M=32ch x N=64px, K=128 ----------
__global__ __launch_bounds__(256) void gemm32_mfma_kernel(
    const float* __restrict__ lin, const float* __restrict__ x,
    float* __restrict__ y) {
  const int Ci = 128, HW = 1024;
  __shared__ unsigned int A_lds[32 * 66];
  __shared__ unsigned int B_lds[64 * 66];
  int b = blockIdx.z;
  int row0 = blockIdx.y * 32, col0 = blockIdx.x * 64;
  const float* xb = x + (size_t)b * Ci * HW;
  float* yb = y + (size_t)b * CC * HW;
  int tid = threadIdx.x;

  {
    int row = tid >> 3, kc = (tid & 7) * 16;
    const float* ap = &lin[(row0 + row) * Ci + kc];
    unsigned int* dst = &A_lds[row * 66 + (kc >> 1)];
#pragma unroll
    for (int i = 0; i < 4; ++i) {
      float4 v = *reinterpret_cast<const float4*>(ap + i * 4);
      dst[i * 2] = pack2(v.x, v.y);
      dst[i * 2 + 1] = pack2(v.z, v.w);
    }
  }
  {
    int kp = tid >> 2, cg = (tid & 3) * 16;
    const float* b0p = &xb[(size_t)(2 * kp) * HW + col0 + cg];
    const float* b1p = &xb[(size_t)(2 * kp + 1) * HW + col0 + cg];
#pragma unroll
    for (int q = 0; q < 4; ++q) {
      float4 v0 = *reinterpret_cast<const float4*>(b0p + q * 4);
      float4 v1 = *reinterpret_cast<const float4*>(b1p + q * 4);
      unsigned int* bp_ = &B_lds[(cg + q * 4) * 66 + kp];
      bp_[0 * 66] = pack2(v0.x, v1.x);
      bp_[1 * 66] = pack2(v0.y, v1.y);
      bp_[2 * 66] = pack2(v0.z, v1.z);
      bp_[3 * 66] = pack2(v0.w, v1.w);
    }
  }
  __syncthreads();

  int w = tid >> 6, l = tid & 63;
  int lr = l & 15, lq = l >> 4;
  int rs = (w & 1) * 16;
  int ct0 = (w >> 1) * 2;
  f32x4 acc0 = {0.f, 0.f, 0.f, 0.f};
  f32x4 acc1 = acc0;
  const unsigned int* arow = &A_lds[(rs + lr) * 66 + 2 * lq];
  const unsigned int* bc0 = &B_lds[(ct0 * 16 + lr) * 66 + 2 * lq];
  const unsigned int* bc1 = &B_lds[((ct0 + 1) * 16 + lr) * 66 + 2 * lq];
#pragma unroll
  for (int s = 0; s < 8; ++s) {
    f16x4 af = *reinterpret_cast<const f16x4*>(arow + s * 8);
    f16x4 b0 = *reinterpret_cast<const f16x4*>(bc0 + s * 8);
    f16x4 b1 = *reinterpret_cast<const f16x4*>(bc1 + s * 8);
    acc0 = __builtin_amdgcn_mfma_f32_16x16x16f16(af, b0, acc0, 0, 0, 0);
    acc1 = __builtin_amdgcn_mfma_f32_16x16x16f16(af, b1, acc1, 0, 0, 0);
  }
#pragma unroll
  for (int i = 0; i < 4; ++i) {
    float* yr = yb + (size_t)(row0 + rs + lq * 4 + i) * HW + col0 + ct0 * 16 + lr;
    yr[0]  = acc0[i];
    yr[16] = acc1[i];
  }
}

// ---------------- fused sample(64x64) + MaxPool2d_G -> 32x32, 256 threads ---------
// Phases 2/3: per-wave 16-row/col ring-slides; conflict-free LDS
// (phase-2 reads contiguous; cb2 transposed [u][r] stride 65 -> writes/reads 2-way max).
__global__ __launch_bounds__(256, 4) void sampmax_kernel(
    const float* __restrict__ y, const float* __restrict__ geo,
    const float* __restrict__ box, float* __restrict__ out) {
  __shared__ __align__(16) float sp[64 * 68];
  __shared__ __align__(16) float arena[67 * 68];  // pl (ph0-1) then cb2[u*65+r] (ph2-3)
  __shared__ float wv[4];
  __shared__ int wi[4];
  __shared__ int am_s;
  float* pl = arena;
  float* cb2 = arena;

  int bc = blockIdx.x;
  int c = bc & (CC - 1);
  int tid = threadIdx.x;

  if (tid < 68) {
    pl[tid] = 0.0f; pl[65 * 68 + tid] = 0.0f; pl[66 * 68 + tid] = 0.0f;
  } else if (tid < 132) {
    int r = tid - 67;
    pl[r * 68 + 0] = 0.0f; pl[r * 68 + 65] = 0.0f; pl[r * 68 + 66] = 0.0f;
  }
  {
    const float* plane = y + (size_t)bc * 4096;
#pragma unroll
    for (int k = 0; k < 4; ++k) {
      int i4 = tid + k * 256;
      float4 f = *reinterpret_cast<const float4*>(&plane[i4 * 4]);
      int h = i4 >> 4, w = (i4 & 15) * 4;
      float* d = &pl[(h + 1) * 68 + w + 1];
      d[0] = f.x; d[1] = f.y; d[2] = f.z; d[3] = f.w;
    }
  }
  __syncthreads();

  {
    const float* g = geo + c * 6;
    const float* bx = box + c * 6;
    float a0 = 32.0f * g[0], a1 = 32.0f * g[1], a2 = 32.0f * g[2] + 31.5f;
    float a3 = 32.0f * g[3], a4 = 32.0f * g[4], a5 = 32.0f * g[5] + 31.5f;
    float c0 = 32.0f * bx[0], c1 = 32.0f * bx[1], c2 = 32.0f * bx[2] + 31.5f;
    float c3 = 32.0f * bx[3], c4 = 32.0f * bx[4], c5 = 32.0f * bx[5] + 31.5f;
#pragma unroll
    for (int k = 0; k < 16; ++k) {
      int px = tid + k * 256;
      int h = px >> 6, w = px & 63;
      float xs = (2.0f * w + 1.0f) / 64.0f - 1.0f;
      float ys = (2.0f * h + 1.0f) / 64.0f - 1.0f;
      float ix = fmaf(a0, xs, fmaf(a1, ys, a2));
      float iy = fmaf(a3, xs, fmaf(a4, ys, a5));
      float samp = sample_pad(pl, 68, 64.0f, ix, iy);
      float bix = fmaf(c0, xs, fmaf(c1, ys, c2));
      float biy = fmaf(c3, xs, fmaf(c4, ys, c5));
      sp[h * 68 + w] = samp * box_mask(bix, biy, 63.0f);
    }
  }
  __syncthreads();

  // Phase 2: vertical 32-row box sums. Wave w -> output rows w*16..w*16+15; lane = col.
  {
    int wv_ = tid >> 6;
    int u = tid & 63;
    int R0 = wv_ * 16;
    float ring[32];
    float S = 0.f;
#pragma unroll
    for (int j = 0; j < 32; ++j) {
      int r = R0 - 16 + j;
      bool valid = (r >= 0) && (r < 64);
      int rc = valid ? r : 0;
      float v = sp[rc * 68 + u];
      v = valid ? v : 0.0f;
      ring[j] = v;
      S += v;
    }
#pragma unroll
    for (int t = 0; t < 16; ++t) {
      cb2[u * 65 + R0 + t] = S;
      int rin = R0 + 16 + t;
      bool vin = rin < 64;
      int rc = vin ? rin : 0;
      float fin = sp[rc * 68 + u];
      fin = vin ? fin : 0.0f;
      S += fin - ring[t];
    }
  }
  __syncthreads();

  // Phase 3: horizontal 32-col box sums + argmax. Wave w -> cols w*16..; lane = row.
  float best = -3.402823466e+38f;
  int bidx = 0x7fffffff;
  {
    int wv_ = tid >> 6;
    int lane_r = tid & 63;
    int C0 = wv_ * 16;
    float ring2[32];
    float S2 = 0.f;
#pragma unroll
    for (int j = 0; j < 32; ++j) {
      int uu = C0 - 16 + j;
      bool valid = (uu >= 0) && (uu < 64);
      int uc = valid ? uu : 0;
      float v = cb2[uc * 65 + lane_r];
      v = valid ? v : 0.0f;
      ring2[j] = v;
      S2 += v;
    }
#pragma unroll
    for (int t = 0; t < 16; ++t) {
      int i = (lane_r << 6) + C0 + t;
      if (S2 > best) { best = S2; bidx = i; }
      int uin = C0 + 16 + t;
      bool vin = uin < 64;
      int uc = vin ? uin : 0;
      float fin = cb2[uc * 65 + lane_r];
      fin = vin ? fin : 0.0f;
      S2 += fin - ring2[t];
    }
  }
#pragma unroll
  for (int off = 32; off > 0; off >>= 1) {
    float v2 = __shfl_down(best, off);
    int i2 = __shfl_down(bidx, off);
    if (v2 > best || (v2 == best && i2 < bidx)) { best = v2; bidx = i2; }
  }
  if ((tid & 63) == 0) { wv[tid >> 6] = best; wi[tid >> 6] = bidx; }
  __syncthreads();
  if (tid == 0) {
    float bv = wv[0]; int bi = wi[0];
#pragma unroll
    for (int k = 1; k < 4; ++k)
      if (wv[k] > bv || (wv[k] == bv && wi[k] < bi)) { bv = wv[k]; bi = wi[k]; }
    am_s = bi;
  }
  __syncthreads();

  int am = am_s;
  int r = am >> 6, cx = am & 63;
  float* o = out + (size_t)bc * 1024;
#pragma unroll
  for (int k = 0; k < 4; ++k) {
    int idx = tid + k * 256;
    int oi = idx >> 5, oj = idx & 31;
    int rr = r + oi - 16, cj = cx + oj - 16;
    bool v = (rr >= 0) && (rr < 64) && (cj >= 0) && (cj < 64);
    int rrc = v ? rr : 0, cjc = v ? cj : 0;
    o[idx] = v ? sp[rrc * 68 + cjc] : 0.0f;
  }
}

// ---------------- 32x32 sample (+optional mean-pool + dense-head atomics) --------
template <bool POOL>
__global__ __launch_bounds__(256) void sample32_kernel(
    const float* __restrict__ y, const float* __restrict__ geo,
    const float* __restrict__ box, float* __restrict__ out,
    const float* __restrict__ dw, float* __restrict__ head) {
  const int W = 32, HW = 1024;
  __shared__ float pl[35 * 36];
  __shared__ float wred[4];
  int bc = blockIdx.x;
  int c = bc & (CC - 1);
  int b = bc >> 7;
  int tid = threadIdx.x;

  if (tid < 36) {
    pl[tid] = 0.0f; pl[33 * 36 + tid] = 0.0f; pl[34 * 36 + tid] = 0.0f;
  } else if (tid < 68) {
    int r = tid - 35;
    pl[r * 36 + 0] = 0.0f; pl[r * 36 + 33] = 0.0f; pl[r * 36 + 34] = 0.0f; pl[r * 36 + 35] = 0.0f;
  }
  {
    const float* plane = y + (size_t)bc * HW;
    float4 f = *reinterpret_cast<const float4*>(&plane[tid * 4]);
    int h = tid >> 3, w = (tid & 7) * 4;
    float* d = &pl[(h + 1) * 36 + w + 1];
    d[0] = f.x; d[1] = f.y; d[2] = f.z; d[3] = f.w;
  }
  __syncthreads();

  const float* g = geo + c * 6;
  const float* bxp = box + c * 6;
  float a0 = 16.0f * g[0], a1 = 16.0f * g[1], a2 = 16.0f * g[2] + 15.5f;
  float a3 = 16.0f * g[3], a4 = 16.0f * g[4], a5 = 16.0f * g[5] + 15.5f;
  float c0 = 16.0f * bxp[0], c1 = 16.0f * bxp[1], c2 = 16.0f * bxp[2] + 15.5f;
  float c3 = 16.0f * bxp[3], c4 = 16.0f * bxp[4], c5 = 16.0f * bxp[5] + 15.5f;
  float* o = out + (size_t)bc * HW;
  float psum = 0.f;
#pragma unroll
  for (int k = 0; k < 4; ++k) {
    int px = tid + k * 256;
    int h = px >> 5, w = px & 31;
    float xs = (2.0f * w + 1.0f) / W - 1.0f;
    float ys = (2.0f * h + 1.0f) / W - 1.0f;
    float ix = fmaf(a0, xs, fmaf(a1, ys, a2));
    float iy = fmaf(a3, xs, fmaf(a4, ys, a5));
    float samp = sample_pad(pl, 36, 32.0f, ix, iy);
    float bix = fmaf(c0, xs, fmaf(c1, ys, c2));
    float biy = fmaf(c3, xs, fmaf(c4, ys, c5));
    float res = samp * box_mask(bix, biy, 31.0f);
    o[px] = res;
    if (POOL) psum += res;
  }
  if (POOL) {
    int lane = tid & 63, wid = tid >> 6;
    float r = psum;
#pragma unroll
    for (int off = 32; off > 0; off >>= 1) r += __shfl_down(r, off);
    if (lane == 0) wred[wid] = r;
    __syncthreads();
    if (tid < 10) {
      float t = (wred[0] + wred[1] + wred[2] + wred[3]) * (1.0f / 1024.0f);
      atomicAdd(&head[b * 10 + tid], t * dw[tid * 128 + c]);
    }
  }
}

extern "C" void kernel_launch(void* const* d_in, const int* in_sizes, int n_in,
                              void* d_out, int out_size, void* d_ws, size_t ws_size,
                              hipStream_t stream) {
  const float* x     = (const float*)d_in[0];   // [8,3,64,64]
  const float* geo0  = (const float*)d_in[1];   // [128,2,3]
  const float* lin0  = (const float*)d_in[2];   // [128,3]
  const float* box0  = (const float*)d_in[3];   // [128,2,3]
  const float* geos  = (const float*)d_in[4];   // [3,128,2,3]
  const float* lins  = (const float*)d_in[5];   // [3,128,128]
  const float* boxes = (const float*)d_in[6];   // [3,128,2,3]
  const float* dw    = (const float*)d_in[7];   // [10,128]
  const float* db    = (const float*)d_in[8];   // [10]

  float* out  = (float*)d_out;      // [8,10] then feat [8,128,32,32]
  float* feat = out + 80;
  float* ws   = (float*)d_ws;
  float* ws0  = ws;                 // 16 MB regions
  float* ws1  = ws + 4194304;
  float* ws2  = ws + 8388608;

  // inLay: fused combine(Ci=3) + sample -> ws1; also writes head bias
  inlay_sample_kernel<<<dim3(BB * CC), 256, 0, stream>>>(x, lin0, geo0, box0, db, ws1, out);
  // layer 0: f16-MFMA GEMM (64x64 tiles) -> fused sample+maxpool -> 32x32
  gemm64_mfma_kernel<<<dim3(64, 2, BB), 256, 0, stream>>>(lins, ws1, ws0);
  sampmax_kernel<<<dim3(BB * CC), 256, 0, stream>>>(ws0, geos, boxes, ws1);
  // layer 2: f16-MFMA GEMM then sample
  gemm32_mfma_kernel<<<dim3(16, 4, BB), 256, 0, stream>>>(lins + 16384, ws1, ws2);
  sample32_kernel<false><<<dim3(BB * CC), 256, 0, stream>>>(ws2, geos + 768, boxes + 768, ws0, nullptr, nullptr);
  // layer 3: f16-MFMA GEMM then sample + mean-pool + dense head
  gemm32_mfma_kernel<<<dim3(16, 4, BB), 256, 0, stream>>>(lins + 32768, ws0, ws2);
  sample32_kernel<true><<<dim3(BB * CC), 256, 0, stream>>>(ws2, geos + 1536, boxes + 1536, feat, dw, out);
}